// Round 4
// baseline (218.400 us; speedup 1.0000x reference)
//
#include <hip/hip_runtime.h>

// PagedKVCache: out = stack([k_cache.at[page,:,off].set(k_val), same for v])
//   k_cache/v_cache: [4096, 8, 16, 128] fp32 (256 MB each)
//   k_val/v_val:     [32, 512, 8, 128] fp32  (64 MB each)
//   slot_mapping:    [32, 512] int (16384 tokens)
//   out:             [2, 4096, 8, 16, 128] fp32 (512 MB)
//
// Gather formulation: map[slot] = overwriting token (else -1), then one
// streaming pass writes every output float4 exactly once.
// R4: split K/V into separate blocks -> each block is a pure 1-load+1-store
// stream over one page of one cache half (64 KB in, 64 KB out). nt loads
// (read-once, keep L2 for the map), normal stores (write-combine in L2).

#define NP   4096
#define NH   8
#define PG   16
#define HD   128
#define NTOK (32 * 512)
#define NSLOT (NP * PG)          // 65536
#define ROWF4 (HD / 4)           // 32
#define PAGEF4 (NH * PG * ROWF4) // 4096 float4 per page per cache half

static constexpr int CACHE_F4 = NP * PAGEF4; // 16,777,216 (fits int32)

typedef float f32x4 __attribute__((ext_vector_type(4)));

__global__ void pagedkv_build_map(const int* __restrict__ slots,
                                  int* __restrict__ map) {
    int t = blockIdx.x * blockDim.x + threadIdx.x;
    if (t < NTOK) map[slots[t]] = t;
}

// grid = 2*NP. Block b: half = b&1 (0=K,1=V), page = b>>1.
// 16 iterations x 256 threads x 16 B = 64 KB read + 64 KB written per block.
__global__ __launch_bounds__(256) void pagedkv_gather(
        const f32x4* __restrict__ kc,
        const f32x4* __restrict__ vc,
        const f32x4* __restrict__ kv,
        const f32x4* __restrict__ vv,
        const int* __restrict__ map,
        f32x4* __restrict__ out) {
    const int half = blockIdx.x & 1;
    const int page = blockIdx.x >> 1;

    __shared__ int toks[PG];
    if (threadIdx.x < PG) toks[threadIdx.x] = map[(page << 4) + threadIdx.x];

    const f32x4* __restrict__ cache = half ? vc : kc;
    const f32x4* __restrict__ vals  = half ? vv : kv;
    f32x4* __restrict__ dst = out + (half ? CACHE_F4 : 0);

    const int pbase = page * PAGEF4;
    __syncthreads();

#pragma unroll
    for (int it = 0; it < PAGEF4 / 256; ++it) {  // 16 iterations
        const int i   = it * 256 + (int)threadIdx.x; // 0..4095 within page
        const int d4  = i & 31;
        const int off = (i >> 5) & 15;
        const int h   = i >> 9;
        const int tok = toks[off];
        const int gi  = pbase + i;
        // branch-free source select: token row or old cache row
        const int s = (tok * NH + h) * ROWF4 + d4;   // valid only if tok>=0
        const f32x4* src = (tok >= 0) ? (vals + s) : (cache + gi);
        f32x4 x = __builtin_nontemporal_load(src);
        dst[gi] = x;
    }
}

extern "C" void kernel_launch(void* const* d_in, const int* in_sizes, int n_in,
                              void* d_out, int out_size, void* d_ws, size_t ws_size,
                              hipStream_t stream) {
    const f32x4* kc    = (const f32x4*)d_in[0];
    const f32x4* vc    = (const f32x4*)d_in[1];
    const f32x4* kv    = (const f32x4*)d_in[2];
    const f32x4* vv    = (const f32x4*)d_in[3];
    const int*   slots = (const int*)d_in[4];
    f32x4* out = (f32x4*)d_out;
    int*   map = (int*)d_ws;   // 65536 ints = 256 KB

    hipMemsetAsync(map, 0xFF, NSLOT * sizeof(int), stream);   // map[:] = -1
    pagedkv_build_map<<<NTOK / 256, 256, 0, stream>>>(slots, map);
    pagedkv_gather<<<2 * NP, 256, 0, stream>>>(kc, vc, kv, vv, map, out);
}

// Round 5
// 202.494 us; speedup vs baseline: 1.0786x; 1.0786x over previous
//
#include <hip/hip_runtime.h>

// PagedKVCache: out = stack([k_cache.at[page,:,off].set(k_val), same for v])
//   k_cache/v_cache: [4096, 8, 16, 128] fp32 (256 MB each)
//   k_val/v_val:     [32, 512, 8, 128] fp32  (64 MB each)
//   slot_mapping:    [32, 512] int (16384 tokens)
//   out:             [2, 4096, 8, 16, 128] fp32 (512 MB)
//
// Gather formulation: map[slot] = overwriting token (else -1). One block per
// page writes every output float4 of that page exactly once (K and V).
// R5: per-page specialization (block-uniform branch from the 16 map entries):
//   - untouched page  -> pure sequential copy (contiguous R, contiguous W)
//   - fully-overwritten page -> source-ORDER iteration: reads from vals are
//     4 KB-contiguous per slot (kv[tok*256 + tid]); the 512 B-chunk
//     transposition moves to the WRITE side where write-back L2 absorbs it.
//   - mixed page -> general per-lane select (correct for any mapping).

#define NP   4096
#define NH   8
#define PG   16
#define HD   128
#define NTOK (32 * 512)
#define NSLOT (NP * PG)          // 65536
#define ROWF4 (HD / 4)           // 32
#define PAGEF4 (NH * PG * ROWF4) // 4096 float4 per page per cache half

static constexpr int CACHE_F4 = NP * PAGEF4; // 16,777,216 (fits int32)

typedef float f32x4 __attribute__((ext_vector_type(4)));

__global__ void pagedkv_build_map(const int* __restrict__ slots,
                                  int* __restrict__ map) {
    int t = blockIdx.x * blockDim.x + threadIdx.x;
    if (t < NTOK) map[slots[t]] = t;
}

__global__ __launch_bounds__(256) void pagedkv_gather(
        const f32x4* __restrict__ kc,
        const f32x4* __restrict__ vc,
        const f32x4* __restrict__ kv,
        const f32x4* __restrict__ vv,
        const int* __restrict__ map,
        f32x4* __restrict__ out) {
    __shared__ int toks[PG];
    const int page = blockIdx.x;
    const int tid  = (int)threadIdx.x;
    if (tid < PG) toks[tid] = map[(page << 4) + tid];
    __syncthreads();

    int nneg = 0;
#pragma unroll
    for (int o = 0; o < PG; ++o) nneg += (toks[o] < 0) ? 1 : 0;

    const int pbase = page * PAGEF4;
    f32x4* __restrict__ outk = out;
    f32x4* __restrict__ outv = out + CACHE_F4;

    if (nneg == PG) {
        // ---- untouched page: pure streaming copy (1 KB/wave contiguous) ----
#pragma unroll
        for (int it = 0; it < PAGEF4 / 256; ++it) {
            const int gi = pbase + it * 256 + tid;
            f32x4 k = __builtin_nontemporal_load(kc + gi);
            f32x4 v = __builtin_nontemporal_load(vc + gi);
            __builtin_nontemporal_store(k, outk + gi);
            __builtin_nontemporal_store(v, outv + gi);
        }
    } else if (nneg == 0) {
        // ---- fully-overwritten page: source-sequential val reads ----
        // thread -> (h = tid>>5, d4 = tid&31); token row (tok*NH+h)*32+d4
        //         = tok*256 + tid  (4 KB contiguous per slot across block)
        const int h  = tid >> 5;
        const int d4 = tid & 31;
        const int go = pbase + (h << 9) + d4;     // + (o<<5) per slot
#pragma unroll
        for (int o = 0; o < PG; ++o) {
            const int tok = toks[o];
            const int s   = tok * 256 + tid;
            f32x4 k = __builtin_nontemporal_load(kv + s);
            f32x4 v = __builtin_nontemporal_load(vv + s);
            __builtin_nontemporal_store(k, outk + go + (o << 5));
            __builtin_nontemporal_store(v, outv + go + (o << 5));
        }
    } else {
        // ---- mixed page: general per-lane source select ----
#pragma unroll
        for (int it = 0; it < PAGEF4 / 256; ++it) {
            const int i   = it * 256 + tid;
            const int d4  = i & 31;
            const int off = (i >> 5) & 15;
            const int h   = i >> 9;
            const int tok = toks[off];
            const int gi  = pbase + i;
            const int s   = (tok * NH + h) * ROWF4 + d4;
            const f32x4* sk = (tok >= 0) ? (kv + s) : (kc + gi);
            const f32x4* sv = (tok >= 0) ? (vv + s) : (vc + gi);
            f32x4 k = __builtin_nontemporal_load(sk);
            f32x4 v = __builtin_nontemporal_load(sv);
            __builtin_nontemporal_store(k, outk + gi);
            __builtin_nontemporal_store(v, outv + gi);
        }
    }
}

extern "C" void kernel_launch(void* const* d_in, const int* in_sizes, int n_in,
                              void* d_out, int out_size, void* d_ws, size_t ws_size,
                              hipStream_t stream) {
    const f32x4* kc    = (const f32x4*)d_in[0];
    const f32x4* vc    = (const f32x4*)d_in[1];
    const f32x4* kv    = (const f32x4*)d_in[2];
    const f32x4* vv    = (const f32x4*)d_in[3];
    const int*   slots = (const int*)d_in[4];
    f32x4* out = (f32x4*)d_out;
    int*   map = (int*)d_ws;   // 65536 ints = 256 KB

    hipMemsetAsync(map, 0xFF, NSLOT * sizeof(int), stream);   // map[:] = -1
    pagedkv_build_map<<<NTOK / 256, 256, 0, stream>>>(slots, map);
    pagedkv_gather<<<NP, 256, 0, stream>>>(kc, vc, kv, vv, map, out);
}

// Round 6
// 201.693 us; speedup vs baseline: 1.0828x; 1.0040x over previous
//
#include <hip/hip_runtime.h>

// PagedKVCache: out = stack([k_cache.at[page,:,off].set(k_val), same for v])
//   k_cache/v_cache: [4096, 8, 16, 128] fp32 (256 MB each)
//   k_val/v_val:     [32, 512, 8, 128] fp32  (64 MB each)
//   slot_mapping:    [32, 512] int (16384 tokens)
//   out:             [2, 4096, 8, 16, 128] fp32 (512 MB)
//
// Gather formulation: map[slot] = overwriting token (else -1). One block per
// page writes every output float4 of that page exactly once (K and V).
// R6: fully-overwritten pages transpose through LDS so BOTH global sides are
// contiguous: stage 8 tokens x 4 KB (contiguous reads) into 32 KB LDS, then
// drain 8 contiguous 4 KB chunks (one per head). Untouched pages remain a
// pure streaming copy; mixed pages use the general per-lane select.

#define NP   4096
#define NH   8
#define PG   16
#define HD   128
#define NTOK (32 * 512)
#define NSLOT (NP * PG)          // 65536
#define ROWF4 (HD / 4)           // 32
#define PAGEF4 (NH * PG * ROWF4) // 4096 float4 per page per cache half

static constexpr int CACHE_F4 = NP * PAGEF4; // 16,777,216 (fits int32)

typedef float f32x4 __attribute__((ext_vector_type(4)));

__global__ void pagedkv_build_map(const int* __restrict__ slots,
                                  int* __restrict__ map) {
    int t = blockIdx.x * blockDim.x + threadIdx.x;
    if (t < NTOK) map[slots[t]] = t;
}

__global__ __launch_bounds__(256) void pagedkv_gather(
        const f32x4* __restrict__ kc,
        const f32x4* __restrict__ vc,
        const f32x4* __restrict__ kv,
        const f32x4* __restrict__ vv,
        const int* __restrict__ map,
        f32x4* __restrict__ out) {
    __shared__ int toks[PG];
    __shared__ f32x4 lds[8 * 256];   // 32 KB: 8 tokens x 256 f4 (4 KB each)

    const int page = blockIdx.x;
    const int tid  = (int)threadIdx.x;
    if (tid < PG) toks[tid] = map[(page << 4) + tid];
    __syncthreads();

    int nneg = 0;
#pragma unroll
    for (int o = 0; o < PG; ++o) nneg += (toks[o] < 0) ? 1 : 0;

    const int pbase = page * PAGEF4;
    f32x4* __restrict__ outk = out;
    f32x4* __restrict__ outv = out + CACHE_F4;

    if (nneg == PG) {
        // ---- untouched page: pure streaming copy (1 KB/wave contiguous) ----
#pragma unroll
        for (int it = 0; it < PAGEF4 / 256; ++it) {
            const int gi = pbase + it * 256 + tid;
            f32x4 k = __builtin_nontemporal_load(kc + gi);
            f32x4 v = __builtin_nontemporal_load(vc + gi);
            __builtin_nontemporal_store(k, outk + gi);
            __builtin_nontemporal_store(v, outv + gi);
        }
    } else if (nneg == 0) {
        // ---- fully-overwritten page: LDS transpose, both sides contiguous --
        // Token o's K-rows are kv[tok*256 .. tok*256+255]  (4 KB contiguous).
        // Output wants [h][off][d4]; stage [o][h][d4] in LDS, drain per-h.
        const int off = tid >> 5;        // 0..7 within chunk
        const int d4  = tid & 31;
#pragma unroll
        for (int half = 0; half < 2; ++half) {
            const f32x4* __restrict__ vals = half ? vv : kv;
            f32x4* __restrict__ dsth       = half ? outv : outk;
#pragma unroll
            for (int c = 0; c < 2; ++c) {          // offs c*8 .. c*8+7
#pragma unroll
                for (int o = 0; o < 8; ++o) {      // stage 8 tokens, 4 KB each
                    const int tok = toks[c * 8 + o];
                    lds[o * 256 + tid] =
                        __builtin_nontemporal_load(vals + tok * 256 + tid);
                }
                __syncthreads();
#pragma unroll
                for (int h = 0; h < 8; ++h) {      // drain 8 x 4 KB contiguous
                    f32x4 x = lds[off * 256 + h * 32 + d4];
                    __builtin_nontemporal_store(
                        x, dsth + pbase + (h << 9) + ((c * 8 + off) << 5) + d4);
                }
                __syncthreads();
            }
        }
    } else {
        // ---- mixed page: general per-lane source select ----
#pragma unroll
        for (int it = 0; it < PAGEF4 / 256; ++it) {
            const int i    = it * 256 + tid;
            const int d4   = i & 31;
            const int offm = (i >> 5) & 15;
            const int h    = i >> 9;
            const int tok  = toks[offm];
            const int gi   = pbase + i;
            const int s    = (tok * NH + h) * ROWF4 + d4;
            const f32x4* sk = (tok >= 0) ? (kv + s) : (kc + gi);
            const f32x4* sv = (tok >= 0) ? (vv + s) : (vc + gi);
            f32x4 k = __builtin_nontemporal_load(sk);
            f32x4 v = __builtin_nontemporal_load(sv);
            __builtin_nontemporal_store(k, outk + gi);
            __builtin_nontemporal_store(v, outv + gi);
        }
    }
}

extern "C" void kernel_launch(void* const* d_in, const int* in_sizes, int n_in,
                              void* d_out, int out_size, void* d_ws, size_t ws_size,
                              hipStream_t stream) {
    const f32x4* kc    = (const f32x4*)d_in[0];
    const f32x4* vc    = (const f32x4*)d_in[1];
    const f32x4* kv    = (const f32x4*)d_in[2];
    const f32x4* vv    = (const f32x4*)d_in[3];
    const int*   slots = (const int*)d_in[4];
    f32x4* out = (f32x4*)d_out;
    int*   map = (int*)d_ws;   // 65536 ints = 256 KB

    hipMemsetAsync(map, 0xFF, NSLOT * sizeof(int), stream);   // map[:] = -1
    pagedkv_build_map<<<NTOK / 256, 256, 0, stream>>>(slots, map);
    pagedkv_gather<<<NP, 256, 0, stream>>>(kc, vc, kv, vv, map, out);
}